// Round 8
// baseline (108.167 us; speedup 1.0000x reference)
//
#include <hip/hip_runtime.h>
#include <hip/hip_bf16.h>

#define IN_CH   128
#define HIDDEN  256
#define H2DIM   128
#define KS1     17             // GEMM1 k-steps total (K=544); pass A: 0..7, pass B: 8..16
#define KS2     8              // GEMM2 k-steps (K=256)
#define NT1     16             // 256/16 n-tiles in GEMM1
#define NT2     8              // 128/16 n-tiles in GEMM2
#define FSTR    296            // feats LDS k-stride (ushort) for the half buffer
#define H1S     264            // h1 overlay stride (ushort)
#define CAP     64             // adjacency-list cap (fallback if deg>CAP)
#define T1PACK  (NT1*KS1*64)   // 17408
#define T2PACK  (NT2*KS2*64)   // 4096

typedef short short8v __attribute__((ext_vector_type(8)));
typedef float f32x4   __attribute__((ext_vector_type(4)));

__device__ __forceinline__ ushort f2bf(float f) {
  union { float f; uint32_t u; } c; c.f = f;
  uint32_t u = c.u + 0x7FFFu + ((c.u >> 16) & 1u);   // RNE
  return (ushort)(u >> 16);
}
__device__ __forceinline__ float bf2f(ushort h) {
  union { uint32_t u; float f; } c; c.u = ((uint32_t)h) << 16;
  return c.f;
}
// packed RNE f32x2 -> bf16x2 via v_cvt_pk_bf16_f32
__device__ __forceinline__ uint32_t pk2(float a, float b) {
  __hip_bfloat162 h = __float22bfloat162_rn(make_float2(a, b));
  union { __hip_bfloat162 h; uint32_t u; } c; c.h = h;
  return c.u;
}
__device__ __forceinline__ uint4 pack8(float4 lo, float4 hi) {
  uint4 r;
  r.x = pk2(lo.x, lo.y); r.y = pk2(lo.z, lo.w);
  r.z = pk2(hi.x, hi.y); r.w = pk2(hi.z, hi.w);
  return r;
}

// ---------------- kernel 1: zero bitset + pack W1(K-folded)/W2 ----------------
// W1' k-order: [0,128): xu(A+E); [128,256): xv(B+E); [256,384): prod C;
// [384,512): absdiff D; [512,516): scalars; [516,544): zero pad
__global__ void k_prep(const float* __restrict__ W1, const float* __restrict__ W2,
                       ushort* __restrict__ w1p, ushort* __restrict__ w2p,
                       uint32_t* __restrict__ bits, int nwords) {
  int t = blockIdx.x * blockDim.x + threadIdx.x;
  if (t < T1PACK) {
    int l = t & 63;
    int rest = t >> 6;
    int ks = rest % KS1;
    int nt = rest / KS1;
    int n  = nt * 16 + (l & 15);
    int k0 = ks * 32 + (l >> 4) * 8;
    short8v v;
    #pragma unroll
    for (int j = 0; j < 8; ++j) {
      int k = k0 + j;
      float val;
      if (k < 128)      val = W1[(size_t)k * HIDDEN + n] + W1[(size_t)(512 + k) * HIDDEN + n];
      else if (k < 256) val = W1[(size_t)k * HIDDEN + n] + W1[(size_t)(384 + k) * HIDDEN + n];
      else if (k < 512) val = W1[(size_t)k * HIDDEN + n];
      else if (k < 516) val = W1[(size_t)(k + 128) * HIDDEN + n];   // rows 640..643
      else              val = 0.f;
      v[j] = (short)f2bf(val);
    }
    *(short8v*)(w1p + (size_t)t * 8) = v;
  } else if (t < T1PACK + T2PACK) {
    int t2 = t - T1PACK;
    int l = t2 & 63;
    int rest = t2 >> 6;
    int ks = rest % KS2;
    int nt = rest / KS2;
    int n  = nt * 16 + (l & 15);
    int k0 = ks * 32 + (l >> 4) * 8;
    short8v v;
    #pragma unroll
    for (int j = 0; j < 8; ++j)
      v[j] = (short)f2bf(W2[(size_t)(k0 + j) * H2DIM + n]);
    *(short8v*)(w2p + (size_t)t2 * 8) = v;
  }
  int stride = gridDim.x * blockDim.x;
  for (int i = t; i < nwords; i += stride) bits[i] = 0u;
}

// ---------------- kernel 2: build adjacency bitset ----------------
__global__ void k_build_adj(const int* __restrict__ ei, int E, int roww,
                            uint32_t* __restrict__ bits) {
  int e = blockIdx.x * blockDim.x + threadIdx.x;
  if (e >= E) return;
  int u = ei[e];
  int v = ei[E + e];
  if (u == v) return;
  atomicOr((unsigned int*)&bits[(size_t)u * roww + (v >> 5)], 1u << (v & 31));
}

// ---------------- kernel 3: degree stats + adjacency lists + node norms ----
__global__ void k_node_lists(const uint32_t* __restrict__ bits, const float* __restrict__ x,
                             int nnodes, int roww,
                             float* __restrict__ invlog, float* __restrict__ invdeg,
                             int* __restrict__ deg, float* __restrict__ nrm,
                             ushort* __restrict__ adjl) {
  int node = blockIdx.x * (blockDim.x >> 6) + (threadIdx.x >> 6);
  int lane = threadIdx.x & 63;
  if (node >= nnodes) return;
  const uint32_t* row = bits + (size_t)node * roww;
  uint32_t wd[4];
  int c = 0;
  #pragma unroll
  for (int j = 0; j < 4; ++j) { wd[j] = row[lane * 4 + j]; c += __popc(wd[j]); }
  int sum = c;
  #pragma unroll
  for (int off = 1; off < 64; off <<= 1) {
    int t = __shfl_up(sum, off);
    if (lane >= off) sum += t;
  }
  int excl = sum - c;
  int total = __shfl(sum, 63);
  ushort* lst = adjl + (size_t)node * CAP;
  int pos = excl;
  #pragma unroll
  for (int j = 0; j < 4; ++j) {
    uint32_t m = wd[j];
    int base = (lane * 4 + j) * 32;
    while (m) {
      int b = __ffs(m) - 1;
      if (pos < CAP) lst[pos] = (ushort)(base + b);
      ++pos;
      m &= m - 1;
    }
  }
  float2 xa = *(const float2*)(x + (size_t)node * IN_CH + 2 * lane);
  float ss = xa.x * xa.x + xa.y * xa.y;
  #pragma unroll
  for (int off = 32; off; off >>= 1) ss += __shfl_xor(ss, off);
  if (lane == 0) {
    deg[node] = total;
    float d = (float)total;
    invlog[node] = (total > 1) ? 1.0f / logf(d) : 0.0f;
    invdeg[node] = (total > 0) ? 1.0f / d : 0.0f;
    nrm[node] = sqrtf(ss);
  }
}

// ---------------- kernel 4: fused features + pair stats + MFMA MLP ----------
// 64 pairs/block, 512 threads (8 waves). Half-width feats buffer (64x296),
// GEMM1 split into two k-passes (A: xu/xv, B: prod/absdiff re-gathered from L2).
// GEMM3 computed in-register via shfl reduce + LDS atomicAdd. ~38.7KB LDS ->
// 4 blocks/CU; launch_bounds(512,8) pins VGPR<=64 for 8 waves/SIMD.
__global__ __launch_bounds__(512, 8) void k_mlp7(
    const float* __restrict__ x, const int* __restrict__ pairs,
    const uint32_t* __restrict__ bits, int roww,
    const int* __restrict__ deg, const float* __restrict__ nrm,
    const float* __restrict__ invlog, const float* __restrict__ invdeg,
    const ushort* __restrict__ adjl,
    const ushort* __restrict__ w1p, const float* __restrict__ b1,
    const ushort* __restrict__ w2p, const float* __restrict__ b2,
    const float* __restrict__ W3, const float* __restrict__ b3,
    float* __restrict__ out, int P)
{
  __shared__ ushort feats[64 * FSTR];   // 37,888 B; h1 (stride 264) overlays later
  __shared__ float outacc[64];
  __shared__ int us[64], vs[64];

  int tid = threadIdx.x;
  int pb = blockIdx.x * 64;
  int w  = tid >> 6, l = tid & 63;
  int pg = l >> 3, g = l & 7;        // feature build: 8 lanes per pair
  int lr = l & 15;                   // MFMA A row / B,C col within tile
  int lk = l >> 4;                   // MFMA k-group / C row group

  if (tid < 64) {
    int2 pr = ((const int2*)pairs)[pb + tid];
    us[tid] = pr.x; vs[tid] = pr.y;
    outacc[tid] = b3[0];
  }
  __syncthreads();

  int p = w * 8 + pg;
  int u = us[p], v = vs[p];
  const float* xu = x + (size_t)u * IN_CH + g * 16;
  const float* xv = x + (size_t)v * IN_CH + g * 16;
  ushort* fpR = feats + p * FSTR;
  ushort* fp  = fpR + g * 16;

  // ---- pass A build: xu -> cols [0,128), xv -> cols [128,256), scalars 256..259,
  //      zero pad 260..287 ----
  {
    float4 a0 = *(const float4*)(xu + 0),  a1 = *(const float4*)(xu + 4);
    float4 a2 = *(const float4*)(xu + 8),  a3 = *(const float4*)(xu + 12);
    float4 b0 = *(const float4*)(xv + 0),  b1v = *(const float4*)(xv + 4);
    float4 b2v = *(const float4*)(xv + 8), b3v = *(const float4*)(xv + 12);
    *(uint4*)(fp)       = pack8(a0, a1);
    *(uint4*)(fp + 8)   = pack8(a2, a3);
    *(uint4*)(fp + 128) = pack8(b0, b1v);
    *(uint4*)(fp + 136) = pack8(b2v, b3v);
    float suv = a0.x*b0.x + a0.y*b0.y + a0.z*b0.z + a0.w*b0.w
              + a1.x*b1v.x + a1.y*b1v.y + a1.z*b1v.z + a1.w*b1v.w
              + a2.x*b2v.x + a2.y*b2v.y + a2.z*b2v.z + a2.w*b2v.w
              + a3.x*b3v.x + a3.y*b3v.y + a3.z*b3v.z + a3.w*b3v.w;
    suv += __shfl_xor(suv, 1);
    suv += __shfl_xor(suv, 2);
    suv += __shfl_xor(suv, 4);
    if (g == 0) fpR[256] = f2bf(suv / fmaxf(nrm[u] * nrm[v], 1e-8f));
    if (g < 7) *(uint2*)(fpR + 260 + 4 * g) = make_uint2(0u, 0u);
  }

  // ---- pair stats (ballot path; rare exact fallback) -> scalars 257..259 ----
  {
    int sdmin[8], snbs[8];
    uint32_t swrd[8];
    bool sfall = false;
    #pragma unroll
    for (int pp = 0; pp < 8; ++pp) {
      int ps_ = w * 8 + pp;
      int uu = us[ps_], vv = vs[ps_];
      int du = deg[uu], dv = deg[vv];
      int nu = adjl[(size_t)uu * CAP + l];
      int nv = adjl[(size_t)vv * CAP + l];
      bool ule = du <= dv;
      sdmin[pp] = ule ? du : dv;
      int o  = ule ? vv : uu;
      int nb = (ule ? nu : nv) & 8191;
      snbs[pp] = nb;
      swrd[pp] = bits[(size_t)o * roww + (nb >> 5)];
      sfall |= (sdmin[pp] > CAP);
    }
    if (!sfall) {
      #pragma unroll
      for (int pp = 0; pp < 8; ++pp) {
        bool h = (l < sdmin[pp]) && ((swrd[pp] >> (snbs[pp] & 31)) & 1u);
        unsigned long long mask = __ballot(h);
        float cnv = (float)__popcll(mask);
        float aa = 0.f, ra = 0.f;
        if (mask) {
          float il = 0.f, ig = 0.f;
          if (h) { il = invlog[snbs[pp]]; ig = invdeg[snbs[pp]]; }
          while (mask) {
            int ln = __ffsll(mask) - 1;
            aa += __shfl(il, ln);
            ra += __shfl(ig, ln);
            mask &= mask - 1;
          }
        }
        if (l == 0) {
          ushort* fq = feats + (w * 8 + pp) * FSTR;
          fq[257] = f2bf(cnv); fq[258] = f2bf(aa); fq[259] = f2bf(ra);
        }
      }
    } else {
      for (int pp = 0; pp < 8; ++pp) {
        int ps_ = w * 8 + pp;
        int uu = us[ps_], vv = vs[ps_];
        float cnL = 0.f, aaL = 0.f, raL = 0.f;
        const uint32_t* ru = bits + (size_t)uu * roww;
        const uint32_t* rv = bits + (size_t)vv * roww;
        for (int wd = l; wd < roww; wd += 64) {
          uint32_t c = ru[wd] & rv[wd];
          cnL += (float)__popc(c);
          while (c) {
            int bb = __ffs(c) - 1;
            int idx = wd * 32 + bb;
            aaL += invlog[idx]; raL += invdeg[idx];
            c &= c - 1;
          }
        }
        #pragma unroll
        for (int off = 32; off; off >>= 1) {
          cnL += __shfl_xor(cnL, off);
          aaL += __shfl_xor(aaL, off);
          raL += __shfl_xor(raL, off);
        }
        if (l == 0) {
          ushort* fq = feats + (w * 8 + pp) * FSTR;
          fq[257] = f2bf(cnL); fq[258] = f2bf(aaL); fq[259] = f2bf(raL);
        }
      }
    }
  }
  __syncthreads();

  // ---- GEMM1 accumulators persist across both k-passes ----
  f32x4 acc[4][2];
  #pragma unroll
  for (int m = 0; m < 4; ++m)
    #pragma unroll
    for (int i = 0; i < 2; ++i) acc[m][i] = (f32x4){0.f, 0.f, 0.f, 0.f};

  const ushort* aB = feats + lr * FSTR + lk * 8;
  const ushort* bW = w1p + (size_t)(w * 2) * KS1 * 512 + l * 8;

  // ---- GEMM1 pass A: ks 0..7 (k 0..255) ----
  {
    short8v bf[2][2];
    #pragma unroll
    for (int i = 0; i < 2; ++i)
      bf[0][i] = *(const short8v*)(bW + (size_t)(i * KS1) * 512);
    #pragma unroll
    for (int ks = 0; ks < 8; ++ks) {
      int cur = ks & 1, nxt = cur ^ 1;
      if (ks + 1 < 8) {
        #pragma unroll
        for (int i = 0; i < 2; ++i)
          bf[nxt][i] = *(const short8v*)(bW + (size_t)(i * KS1 + ks + 1) * 512);
      }
      short8v am[4];
      #pragma unroll
      for (int m = 0; m < 4; ++m)
        am[m] = *(const short8v*)(aB + m * 16 * FSTR + ks * 32);
      #pragma unroll
      for (int i = 0; i < 2; ++i)
        #pragma unroll
        for (int m = 0; m < 4; ++m)
          acc[m][i] = __builtin_amdgcn_mfma_f32_16x16x32_bf16(am[m], bf[cur][i], acc[m][i], 0, 0, 0);
    }
  }
  __syncthreads();   // all waves done reading pass-A cols

  // ---- pass B build: re-gather x (L2-hot), prod -> cols [0,128), absdiff -> [128,256) ----
  {
    float4 a0 = *(const float4*)(xu + 0),  a1 = *(const float4*)(xu + 4);
    float4 a2 = *(const float4*)(xu + 8),  a3 = *(const float4*)(xu + 12);
    float4 b0 = *(const float4*)(xv + 0),  b1v = *(const float4*)(xv + 4);
    float4 b2v = *(const float4*)(xv + 8), b3v = *(const float4*)(xv + 12);
    float4 c0, c1, c2, c3, d0, d1, d2, d3;
    c0.x=a0.x*b0.x;  c0.y=a0.y*b0.y;  c0.z=a0.z*b0.z;  c0.w=a0.w*b0.w;
    c1.x=a1.x*b1v.x; c1.y=a1.y*b1v.y; c1.z=a1.z*b1v.z; c1.w=a1.w*b1v.w;
    c2.x=a2.x*b2v.x; c2.y=a2.y*b2v.y; c2.z=a2.z*b2v.z; c2.w=a2.w*b2v.w;
    c3.x=a3.x*b3v.x; c3.y=a3.y*b3v.y; c3.z=a3.z*b3v.z; c3.w=a3.w*b3v.w;
    d0.x=fabsf(a0.x-b0.x);  d0.y=fabsf(a0.y-b0.y);  d0.z=fabsf(a0.z-b0.z);  d0.w=fabsf(a0.w-b0.w);
    d1.x=fabsf(a1.x-b1v.x); d1.y=fabsf(a1.y-b1v.y); d1.z=fabsf(a1.z-b1v.z); d1.w=fabsf(a1.w-b1v.w);
    d2.x=fabsf(a2.x-b2v.x); d2.y=fabsf(a2.y-b2v.y); d2.z=fabsf(a2.z-b2v.z); d2.w=fabsf(a2.w-b2v.w);
    d3.x=fabsf(a3.x-b3v.x); d3.y=fabsf(a3.y-b3v.y); d3.z=fabsf(a3.z-b3v.z); d3.w=fabsf(a3.w-b3v.w);
    *(uint4*)(fp)       = pack8(c0, c1);
    *(uint4*)(fp + 8)   = pack8(c2, c3);
    *(uint4*)(fp + 128) = pack8(d0, d1);
    *(uint4*)(fp + 136) = pack8(d2, d3);
  }
  __syncthreads();

  // ---- GEMM1 pass B: ks 8..16 (k 256..543; buffer col = (ks-8)*32) ----
  {
    short8v bf[2][2];
    #pragma unroll
    for (int i = 0; i < 2; ++i)
      bf[0][i] = *(const short8v*)(bW + (size_t)(i * KS1 + 8) * 512);
    #pragma unroll
    for (int ks = 8; ks < KS1; ++ks) {
      int cur = ks & 1, nxt = cur ^ 1;
      if (ks + 1 < KS1) {
        #pragma unroll
        for (int i = 0; i < 2; ++i)
          bf[nxt][i] = *(const short8v*)(bW + (size_t)(i * KS1 + ks + 1) * 512);
      }
      short8v am[4];
      #pragma unroll
      for (int m = 0; m < 4; ++m)
        am[m] = *(const short8v*)(aB + m * 16 * FSTR + (ks - 8) * 32);
      #pragma unroll
      for (int i = 0; i < 2; ++i)
        #pragma unroll
        for (int m = 0; m < 4; ++m)
          acc[m][i] = __builtin_amdgcn_mfma_f32_16x16x32_bf16(am[m], bf[cur][i], acc[m][i], 0, 0, 0);
    }
  }

  // bias1 + ReLU + bf16 into regs; overlay h1 into feats after barrier
  uint32_t h1r[2][8];
  #pragma unroll
  for (int i = 0; i < 2; ++i) {
    float bias = b1[(w * 2 + i) * 16 + lr];
    #pragma unroll
    for (int m = 0; m < 4; ++m) {
      float v0 = fmaxf(acc[m][i][0] + bias, 0.f);
      float v1 = fmaxf(acc[m][i][1] + bias, 0.f);
      float v2 = fmaxf(acc[m][i][2] + bias, 0.f);
      float v3 = fmaxf(acc[m][i][3] + bias, 0.f);
      h1r[i][m * 2]     = pk2(v0, v1);
      h1r[i][m * 2 + 1] = pk2(v2, v3);
    }
  }
  __syncthreads();   // pass-B buffer fully consumed

  ushort* h1 = feats;   // flat overlay [row*H1S + col]
  #pragma unroll
  for (int i = 0; i < 2; ++i) {
    int col = (w * 2 + i) * 16 + lr;
    #pragma unroll
    for (int m = 0; m < 4; ++m) {
      int row0 = m * 16 + lk * 4;
      h1[(row0)     * H1S + col] = (ushort)(h1r[i][m * 2]);
      h1[(row0 + 1) * H1S + col] = (ushort)(h1r[i][m * 2] >> 16);
      h1[(row0 + 2) * H1S + col] = (ushort)(h1r[i][m * 2 + 1]);
      h1[(row0 + 3) * H1S + col] = (ushort)(h1r[i][m * 2 + 1] >> 16);
    }
  }
  __syncthreads();

  // ---- GEMM2: h1[64x256] @ W2[256x128]; wave w owns n-tile w ----
  f32x4 acc2[4];
  #pragma unroll
  for (int m = 0; m < 4; ++m) acc2[m] = (f32x4){0.f, 0.f, 0.f, 0.f};

  const ushort* aB2 = h1 + lr * H1S + lk * 8;
  const ushort* bW2 = w2p + (size_t)w * KS2 * 512 + l * 8;

  short8v b2f[2];
  b2f[0] = *(const short8v*)(bW2);

  #pragma unroll
  for (int ks = 0; ks < KS2; ++ks) {
    int cur = ks & 1, nxt = cur ^ 1;
    if (ks + 1 < KS2)
      b2f[nxt] = *(const short8v*)(bW2 + (size_t)(ks + 1) * 512);
    #pragma unroll
    for (int m = 0; m < 4; ++m) {
      short8v am = *(const short8v*)(aB2 + m * 16 * H1S + ks * 32);
      acc2[m] = __builtin_amdgcn_mfma_f32_16x16x32_bf16(am, b2f[cur], acc2[m], 0, 0, 0);
    }
  }

  // ---- GEMM3 in-register: lane col = w*16+lr; reduce over 16 cols then waves ----
  {
    int col = w * 16 + lr;
    float bias = b2[col];
    float w3v = W3[col];
    #pragma unroll
    for (int m = 0; m < 4; ++m) {
      #pragma unroll
      for (int r = 0; r < 4; ++r) {
        float h = fmaxf(acc2[m][r] + bias, 0.f) * w3v;
        h += __shfl_xor(h, 1);
        h += __shfl_xor(h, 2);
        h += __shfl_xor(h, 4);
        h += __shfl_xor(h, 8);
        if (lr == 0) atomicAdd(&outacc[m * 16 + lk * 4 + r], h);
      }
    }
  }
  __syncthreads();

  if (tid < 64) out[pb + tid] = outacc[tid];
}

extern "C" void kernel_launch(void* const* d_in, const int* in_sizes, int n_in,
                              void* d_out, int out_size, void* d_ws, size_t ws_size,
                              hipStream_t stream) {
  const float* x     = (const float*)d_in[0];
  const int*   ei    = (const int*)d_in[1];
  const int*   pairs = (const int*)d_in[2];
  const float* W1    = (const float*)d_in[3];
  const float* b1    = (const float*)d_in[4];
  const float* W2    = (const float*)d_in[5];
  const float* b2    = (const float*)d_in[6];
  const float* W3    = (const float*)d_in[7];
  const float* b3    = (const float*)d_in[8];
  float* out = (float*)d_out;

  int N = in_sizes[0] / IN_CH;       // 8192
  int E = in_sizes[1] / 2;           // 262144
  int P = in_sizes[2] / 2;           // 65536
  int roww = (N + 31) >> 5;          // 256

  char* wsb = (char*)d_ws;
  uint32_t* bits = (uint32_t*)wsb;                       size_t off = (size_t)N * roww * 4;
  float* invlog  = (float*)(wsb + off);                  off += (size_t)N * 4;
  float* invdeg  = (float*)(wsb + off);                  off += (size_t)N * 4;
  int*   deg     = (int*)(wsb + off);                    off += (size_t)N * 4;
  float* nrm     = (float*)(wsb + off);                  off += (size_t)N * 4;
  ushort* adjl   = (ushort*)(wsb + off);                 off += (size_t)N * CAP * 2;
  ushort* w1pack = (ushort*)(wsb + off);                 off += (size_t)T1PACK * 8 * 2;
  ushort* w2pack = (ushort*)(wsb + off);                 off += (size_t)T2PACK * 8 * 2;

  int nwords = N * roww;
  k_prep<<<1024, 256, 0, stream>>>(W1, W2, w1pack, w2pack, bits, nwords);
  k_build_adj<<<(E + 255) / 256, 256, 0, stream>>>(ei, E, roww, bits);
  k_node_lists<<<(N + 3) / 4, 256, 0, stream>>>(bits, x, N, roww, invlog, invdeg, deg, nrm, adjl);
  k_mlp7<<<P / 64, 512, 0, stream>>>(x, pairs, bits, roww, deg, nrm, invlog, invdeg, adjl,
                                     w1pack, b1, w2pack, b2, W3, b3, out, P);
}

// Round 9
// 85.525 us; speedup vs baseline: 1.2647x; 1.2647x over previous
//
#include <hip/hip_runtime.h>
#include <hip/hip_bf16.h>

#define IN_CH   128
#define HIDDEN  256
#define H2DIM   128
#define KS1     17             // GEMM1 k-steps total (K=544); pass A: 0..7, pass B: 8..16
#define KS2     8              // GEMM2 k-steps (K=256)
#define NT1     16             // 256/16 n-tiles in GEMM1
#define NT2     8              // 128/16 n-tiles in GEMM2
#define FSTR    296            // feats LDS k-stride (ushort) for the half buffer
#define H1S     264            // h1 overlay stride (ushort)
#define CAP     64             // adjacency-list cap (fallback if deg>CAP)
#define T1PACK  (NT1*KS1*64)   // 17408
#define T2PACK  (NT2*KS2*64)   // 4096

typedef short short8v __attribute__((ext_vector_type(8)));
typedef float f32x4   __attribute__((ext_vector_type(4)));

__device__ __forceinline__ ushort f2bf(float f) {
  union { float f; uint32_t u; } c; c.f = f;
  uint32_t u = c.u + 0x7FFFu + ((c.u >> 16) & 1u);   // RNE
  return (ushort)(u >> 16);
}
__device__ __forceinline__ float bf2f(ushort h) {
  union { uint32_t u; float f; } c; c.u = ((uint32_t)h) << 16;
  return c.f;
}
__device__ __forceinline__ float bfLo(uint32_t u) { return bf2f((ushort)(u & 0xffffu)); }
__device__ __forceinline__ float bfHi(uint32_t u) { return bf2f((ushort)(u >> 16)); }
// packed RNE f32x2 -> bf16x2 via v_cvt_pk_bf16_f32
__device__ __forceinline__ uint32_t pk2(float a, float b) {
  __hip_bfloat162 h = __float22bfloat162_rn(make_float2(a, b));
  union { __hip_bfloat162 h; uint32_t u; } c; c.h = h;
  return c.u;
}
__device__ __forceinline__ uint4 pack8(float4 lo, float4 hi) {
  uint4 r;
  r.x = pk2(lo.x, lo.y); r.y = pk2(lo.z, lo.w);
  r.z = pk2(hi.x, hi.y); r.w = pk2(hi.z, hi.w);
  return r;
}

// ---------------- kernel 1: zero bitset + pack W1(K-folded)/W2 ----------------
// W1' k-order: [0,128): xu(A+E); [128,256): xv(B+E); [256,384): prod C;
// [384,512): absdiff D; [512,516): scalars; [516,544): zero pad
__global__ void k_prep(const float* __restrict__ W1, const float* __restrict__ W2,
                       ushort* __restrict__ w1p, ushort* __restrict__ w2p,
                       uint32_t* __restrict__ bits, int nwords) {
  int t = blockIdx.x * blockDim.x + threadIdx.x;
  if (t < T1PACK) {
    int l = t & 63;
    int rest = t >> 6;
    int ks = rest % KS1;
    int nt = rest / KS1;
    int n  = nt * 16 + (l & 15);
    int k0 = ks * 32 + (l >> 4) * 8;
    short8v v;
    #pragma unroll
    for (int j = 0; j < 8; ++j) {
      int k = k0 + j;
      float val;
      if (k < 128)      val = W1[(size_t)k * HIDDEN + n] + W1[(size_t)(512 + k) * HIDDEN + n];
      else if (k < 256) val = W1[(size_t)k * HIDDEN + n] + W1[(size_t)(384 + k) * HIDDEN + n];
      else if (k < 512) val = W1[(size_t)k * HIDDEN + n];
      else if (k < 516) val = W1[(size_t)(k + 128) * HIDDEN + n];   // rows 640..643
      else              val = 0.f;
      v[j] = (short)f2bf(val);
    }
    *(short8v*)(w1p + (size_t)t * 8) = v;
  } else if (t < T1PACK + T2PACK) {
    int t2 = t - T1PACK;
    int l = t2 & 63;
    int rest = t2 >> 6;
    int ks = rest % KS2;
    int nt = rest / KS2;
    int n  = nt * 16 + (l & 15);
    int k0 = ks * 32 + (l >> 4) * 8;
    short8v v;
    #pragma unroll
    for (int j = 0; j < 8; ++j)
      v[j] = (short)f2bf(W2[(size_t)(k0 + j) * H2DIM + n]);
    *(short8v*)(w2p + (size_t)t2 * 8) = v;
  }
  int stride = gridDim.x * blockDim.x;
  for (int i = t; i < nwords; i += stride) bits[i] = 0u;
}

// ---------------- kernel 2: build adjacency bitset ----------------
__global__ void k_build_adj(const int* __restrict__ ei, int E, int roww,
                            uint32_t* __restrict__ bits) {
  int e = blockIdx.x * blockDim.x + threadIdx.x;
  if (e >= E) return;
  int u = ei[e];
  int v = ei[E + e];
  if (u == v) return;
  atomicOr((unsigned int*)&bits[(size_t)u * roww + (v >> 5)], 1u << (v & 31));
}

// ---------------- kernel 3: degree stats + adjacency lists + node norms ----
__global__ void k_node_lists(const uint32_t* __restrict__ bits, const float* __restrict__ x,
                             int nnodes, int roww,
                             float* __restrict__ invlog, float* __restrict__ invdeg,
                             int* __restrict__ deg, float* __restrict__ nrm,
                             ushort* __restrict__ adjl) {
  int node = blockIdx.x * (blockDim.x >> 6) + (threadIdx.x >> 6);
  int lane = threadIdx.x & 63;
  if (node >= nnodes) return;
  const uint32_t* row = bits + (size_t)node * roww;
  uint32_t wd[4];
  int c = 0;
  #pragma unroll
  for (int j = 0; j < 4; ++j) { wd[j] = row[lane * 4 + j]; c += __popc(wd[j]); }
  int sum = c;
  #pragma unroll
  for (int off = 1; off < 64; off <<= 1) {
    int t = __shfl_up(sum, off);
    if (lane >= off) sum += t;
  }
  int excl = sum - c;
  int total = __shfl(sum, 63);
  ushort* lst = adjl + (size_t)node * CAP;
  int pos = excl;
  #pragma unroll
  for (int j = 0; j < 4; ++j) {
    uint32_t m = wd[j];
    int base = (lane * 4 + j) * 32;
    while (m) {
      int b = __ffs(m) - 1;
      if (pos < CAP) lst[pos] = (ushort)(base + b);
      ++pos;
      m &= m - 1;
    }
  }
  float2 xa = *(const float2*)(x + (size_t)node * IN_CH + 2 * lane);
  float ss = xa.x * xa.x + xa.y * xa.y;
  #pragma unroll
  for (int off = 32; off; off >>= 1) ss += __shfl_xor(ss, off);
  if (lane == 0) {
    deg[node] = total;
    float d = (float)total;
    invlog[node] = (total > 1) ? 1.0f / logf(d) : 0.0f;
    invdeg[node] = (total > 0) ? 1.0f / d : 0.0f;
    nrm[node] = sqrtf(ss);
  }
}

// ---------------- kernel 4: fused features + pair stats + MFMA MLP ----------
// 64 pairs/block, 512 threads (8 waves). Half-width feats buffer (64x296),
// GEMM1 split into two k-passes; pass B recomputes prod/absdiff from the
// bf16 xu/xv already in LDS (no second x gather). GEMM3 in-register.
// LDS ~38.7KB; launch_bounds(512,6) caps VGPR ~84 (no spill) -> 3-4 blocks/CU.
__global__ __launch_bounds__(512, 6) void k_mlp8(
    const float* __restrict__ x, const int* __restrict__ pairs,
    const uint32_t* __restrict__ bits, int roww,
    const int* __restrict__ deg, const float* __restrict__ nrm,
    const float* __restrict__ invlog, const float* __restrict__ invdeg,
    const ushort* __restrict__ adjl,
    const ushort* __restrict__ w1p, const float* __restrict__ b1,
    const ushort* __restrict__ w2p, const float* __restrict__ b2,
    const float* __restrict__ W3, const float* __restrict__ b3,
    float* __restrict__ out, int P)
{
  __shared__ ushort feats[64 * FSTR];   // 37,888 B; h1 (stride 264) overlays later
  __shared__ float outacc[64];
  __shared__ int us[64], vs[64];

  int tid = threadIdx.x;
  int pb = blockIdx.x * 64;
  int w  = tid >> 6, l = tid & 63;
  int pg = l >> 3, g = l & 7;        // feature build: 8 lanes per pair
  int lr = l & 15;                   // MFMA A row / B,C col within tile
  int lk = l >> 4;                   // MFMA k-group / C row group

  if (tid < 64) {
    int2 pr = ((const int2*)pairs)[pb + tid];
    us[tid] = pr.x; vs[tid] = pr.y;
    outacc[tid] = b3[0];
  }
  __syncthreads();

  int p = w * 8 + pg;
  int u = us[p], v = vs[p];
  const float* xu = x + (size_t)u * IN_CH + g * 16;
  const float* xv = x + (size_t)v * IN_CH + g * 16;
  ushort* fpR = feats + p * FSTR;
  ushort* fp  = fpR + g * 16;

  // ---- pass A build: xu -> cols [0,128), xv -> cols [128,256), scalars 256..259,
  //      zero pad 260..287 ----
  {
    float4 a0 = *(const float4*)(xu + 0),  a1 = *(const float4*)(xu + 4);
    float4 a2 = *(const float4*)(xu + 8),  a3 = *(const float4*)(xu + 12);
    float4 b0 = *(const float4*)(xv + 0),  b1v = *(const float4*)(xv + 4);
    float4 b2v = *(const float4*)(xv + 8), b3v = *(const float4*)(xv + 12);
    *(uint4*)(fp)       = pack8(a0, a1);
    *(uint4*)(fp + 8)   = pack8(a2, a3);
    *(uint4*)(fp + 128) = pack8(b0, b1v);
    *(uint4*)(fp + 136) = pack8(b2v, b3v);
    float suv = a0.x*b0.x + a0.y*b0.y + a0.z*b0.z + a0.w*b0.w
              + a1.x*b1v.x + a1.y*b1v.y + a1.z*b1v.z + a1.w*b1v.w
              + a2.x*b2v.x + a2.y*b2v.y + a2.z*b2v.z + a2.w*b2v.w
              + a3.x*b3v.x + a3.y*b3v.y + a3.z*b3v.z + a3.w*b3v.w;
    suv += __shfl_xor(suv, 1);
    suv += __shfl_xor(suv, 2);
    suv += __shfl_xor(suv, 4);
    if (g == 0) fpR[256] = f2bf(suv / fmaxf(nrm[u] * nrm[v], 1e-8f));
    if (g < 7) *(uint2*)(fpR + 260 + 4 * g) = make_uint2(0u, 0u);
  }

  // ---- pair stats (ballot path; rare exact fallback) -> scalars 257..259 ----
  {
    int sdmin[8], snbs[8];
    uint32_t swrd[8];
    bool sfall = false;
    #pragma unroll
    for (int pp = 0; pp < 8; ++pp) {
      int ps_ = w * 8 + pp;
      int uu = us[ps_], vv = vs[ps_];
      int du = deg[uu], dv = deg[vv];
      int nu = adjl[(size_t)uu * CAP + l];
      int nv = adjl[(size_t)vv * CAP + l];
      bool ule = du <= dv;
      sdmin[pp] = ule ? du : dv;
      int o  = ule ? vv : uu;
      int nb = (ule ? nu : nv) & 8191;
      snbs[pp] = nb;
      swrd[pp] = bits[(size_t)o * roww + (nb >> 5)];
      sfall |= (sdmin[pp] > CAP);
    }
    if (!sfall) {
      #pragma unroll
      for (int pp = 0; pp < 8; ++pp) {
        bool h = (l < sdmin[pp]) && ((swrd[pp] >> (snbs[pp] & 31)) & 1u);
        unsigned long long mask = __ballot(h);
        float cnv = (float)__popcll(mask);
        float aa = 0.f, ra = 0.f;
        if (mask) {
          float il = 0.f, ig = 0.f;
          if (h) { il = invlog[snbs[pp]]; ig = invdeg[snbs[pp]]; }
          while (mask) {
            int ln = __ffsll(mask) - 1;
            aa += __shfl(il, ln);
            ra += __shfl(ig, ln);
            mask &= mask - 1;
          }
        }
        if (l == 0) {
          ushort* fq = feats + (w * 8 + pp) * FSTR;
          fq[257] = f2bf(cnv); fq[258] = f2bf(aa); fq[259] = f2bf(ra);
        }
      }
    } else {
      for (int pp = 0; pp < 8; ++pp) {
        int ps_ = w * 8 + pp;
        int uu = us[ps_], vv = vs[ps_];
        float cnL = 0.f, aaL = 0.f, raL = 0.f;
        const uint32_t* ru = bits + (size_t)uu * roww;
        const uint32_t* rv = bits + (size_t)vv * roww;
        for (int wd = l; wd < roww; wd += 64) {
          uint32_t c = ru[wd] & rv[wd];
          cnL += (float)__popc(c);
          while (c) {
            int bb = __ffs(c) - 1;
            int idx = wd * 32 + bb;
            aaL += invlog[idx]; raL += invdeg[idx];
            c &= c - 1;
          }
        }
        #pragma unroll
        for (int off = 32; off; off >>= 1) {
          cnL += __shfl_xor(cnL, off);
          aaL += __shfl_xor(aaL, off);
          raL += __shfl_xor(raL, off);
        }
        if (l == 0) {
          ushort* fq = feats + (w * 8 + pp) * FSTR;
          fq[257] = f2bf(cnL); fq[258] = f2bf(aaL); fq[259] = f2bf(raL);
        }
      }
    }
  }
  __syncthreads();

  // ---- GEMM1 accumulators persist across both k-passes ----
  f32x4 acc[4][2];
  #pragma unroll
  for (int m = 0; m < 4; ++m)
    #pragma unroll
    for (int i = 0; i < 2; ++i) acc[m][i] = (f32x4){0.f, 0.f, 0.f, 0.f};

  const ushort* aB = feats + lr * FSTR + lk * 8;
  const ushort* bW = w1p + (size_t)(w * 2) * KS1 * 512 + l * 8;

  // ---- GEMM1 pass A: ks 0..7 (k 0..255) ----
  {
    short8v bf[2][2];
    #pragma unroll
    for (int i = 0; i < 2; ++i)
      bf[0][i] = *(const short8v*)(bW + (size_t)(i * KS1) * 512);
    #pragma unroll
    for (int ks = 0; ks < 8; ++ks) {
      int cur = ks & 1, nxt = cur ^ 1;
      if (ks + 1 < 8) {
        #pragma unroll
        for (int i = 0; i < 2; ++i)
          bf[nxt][i] = *(const short8v*)(bW + (size_t)(i * KS1 + ks + 1) * 512);
      }
      short8v am[4];
      #pragma unroll
      for (int m = 0; m < 4; ++m)
        am[m] = *(const short8v*)(aB + m * 16 * FSTR + ks * 32);
      #pragma unroll
      for (int i = 0; i < 2; ++i)
        #pragma unroll
        for (int m = 0; m < 4; ++m)
          acc[m][i] = __builtin_amdgcn_mfma_f32_16x16x32_bf16(am[m], bf[cur][i], acc[m][i], 0, 0, 0);
    }
  }
  __syncthreads();   // all waves done reading pass-A cols

  // ---- pass B build: read bf16 xu/xv back from LDS; prod -> [0,128),
  //      absdiff -> [128,256). Same-thread same-cells: no cross-thread hazard.
  {
    uint4 A0 = *(uint4*)(fp);
    uint4 A1 = *(uint4*)(fp + 8);
    uint4 B0 = *(uint4*)(fp + 128);
    uint4 B1 = *(uint4*)(fp + 136);
    uint4 P0, P1, D0, D1;
    #define PD(Au, Bu, Pu, Du)                                                 \
      {                                                                        \
        float alo = bfLo(Au), ahi = bfHi(Au);                                  \
        float blo = bfLo(Bu), bhi = bfHi(Bu);                                  \
        Pu = pk2(alo * blo, ahi * bhi);                                        \
        Du = pk2(fabsf(alo - blo), fabsf(ahi - bhi));                          \
      }
    PD(A0.x, B0.x, P0.x, D0.x) PD(A0.y, B0.y, P0.y, D0.y)
    PD(A0.z, B0.z, P0.z, D0.z) PD(A0.w, B0.w, P0.w, D0.w)
    PD(A1.x, B1.x, P1.x, D1.x) PD(A1.y, B1.y, P1.y, D1.y)
    PD(A1.z, B1.z, P1.z, D1.z) PD(A1.w, B1.w, P1.w, D1.w)
    #undef PD
    *(uint4*)(fp)       = P0;
    *(uint4*)(fp + 8)   = P1;
    *(uint4*)(fp + 128) = D0;
    *(uint4*)(fp + 136) = D1;
  }
  __syncthreads();

  // ---- GEMM1 pass B: ks 8..16 (k 256..543; buffer col = (ks-8)*32) ----
  {
    short8v bf[2][2];
    #pragma unroll
    for (int i = 0; i < 2; ++i)
      bf[0][i] = *(const short8v*)(bW + (size_t)(i * KS1 + 8) * 512);
    #pragma unroll
    for (int ks = 8; ks < KS1; ++ks) {
      int cur = ks & 1, nxt = cur ^ 1;
      if (ks + 1 < KS1) {
        #pragma unroll
        for (int i = 0; i < 2; ++i)
          bf[nxt][i] = *(const short8v*)(bW + (size_t)(i * KS1 + ks + 1) * 512);
      }
      short8v am[4];
      #pragma unroll
      for (int m = 0; m < 4; ++m)
        am[m] = *(const short8v*)(aB + m * 16 * FSTR + (ks - 8) * 32);
      #pragma unroll
      for (int i = 0; i < 2; ++i)
        #pragma unroll
        for (int m = 0; m < 4; ++m)
          acc[m][i] = __builtin_amdgcn_mfma_f32_16x16x32_bf16(am[m], bf[cur][i], acc[m][i], 0, 0, 0);
    }
  }

  // bias1 + ReLU + bf16 into regs; overlay h1 into feats after barrier
  uint32_t h1r[2][8];
  #pragma unroll
  for (int i = 0; i < 2; ++i) {
    float bias = b1[(w * 2 + i) * 16 + lr];
    #pragma unroll
    for (int m = 0; m < 4; ++m) {
      float v0 = fmaxf(acc[m][i][0] + bias, 0.f);
      float v1 = fmaxf(acc[m][i][1] + bias, 0.f);
      float v2 = fmaxf(acc[m][i][2] + bias, 0.f);
      float v3 = fmaxf(acc[m][i][3] + bias, 0.f);
      h1r[i][m * 2]     = pk2(v0, v1);
      h1r[i][m * 2 + 1] = pk2(v2, v3);
    }
  }
  __syncthreads();   // pass-B buffer fully consumed

  ushort* h1 = feats;   // flat overlay [row*H1S + col]
  #pragma unroll
  for (int i = 0; i < 2; ++i) {
    int col = (w * 2 + i) * 16 + lr;
    #pragma unroll
    for (int m = 0; m < 4; ++m) {
      int row0 = m * 16 + lk * 4;
      h1[(row0)     * H1S + col] = (ushort)(h1r[i][m * 2]);
      h1[(row0 + 1) * H1S + col] = (ushort)(h1r[i][m * 2] >> 16);
      h1[(row0 + 2) * H1S + col] = (ushort)(h1r[i][m * 2 + 1]);
      h1[(row0 + 3) * H1S + col] = (ushort)(h1r[i][m * 2 + 1] >> 16);
    }
  }
  __syncthreads();

  // ---- GEMM2: h1[64x256] @ W2[256x128]; wave w owns n-tile w ----
  f32x4 acc2[4];
  #pragma unroll
  for (int m = 0; m < 4; ++m) acc2[m] = (f32x4){0.f, 0.f, 0.f, 0.f};

  const ushort* aB2 = h1 + lr * H1S + lk * 8;
  const ushort* bW2 = w2p + (size_t)w * KS2 * 512 + l * 8;

  short8v b2f[2];
  b2f[0] = *(const short8v*)(bW2);

  #pragma unroll
  for (int ks = 0; ks < KS2; ++ks) {
    int cur = ks & 1, nxt = cur ^ 1;
    if (ks + 1 < KS2)
      b2f[nxt] = *(const short8v*)(bW2 + (size_t)(ks + 1) * 512);
    #pragma unroll
    for (int m = 0; m < 4; ++m) {
      short8v am = *(const short8v*)(aB2 + m * 16 * H1S + ks * 32);
      acc2[m] = __builtin_amdgcn_mfma_f32_16x16x32_bf16(am, b2f[cur], acc2[m], 0, 0, 0);
    }
  }

  // ---- GEMM3 in-register: lane col = w*16+lr; shfl-reduce then LDS atomicAdd ----
  {
    int col = w * 16 + lr;
    float bias = b2[col];
    float w3v = W3[col];
    #pragma unroll
    for (int m = 0; m < 4; ++m) {
      #pragma unroll
      for (int r = 0; r < 4; ++r) {
        float h = fmaxf(acc2[m][r] + bias, 0.f) * w3v;
        h += __shfl_xor(h, 1);
        h += __shfl_xor(h, 2);
        h += __shfl_xor(h, 4);
        h += __shfl_xor(h, 8);
        if (lr == 0) atomicAdd(&outacc[m * 16 + lk * 4 + r], h);
      }
    }
  }
  __syncthreads();

  if (tid < 64) out[pb + tid] = outacc[tid];
}

extern "C" void kernel_launch(void* const* d_in, const int* in_sizes, int n_in,
                              void* d_out, int out_size, void* d_ws, size_t ws_size,
                              hipStream_t stream) {
  const float* x     = (const float*)d_in[0];
  const int*   ei    = (const int*)d_in[1];
  const int*   pairs = (const int*)d_in[2];
  const float* W1    = (const float*)d_in[3];
  const float* b1    = (const float*)d_in[4];
  const float* W2    = (const float*)d_in[5];
  const float* b2    = (const float*)d_in[6];
  const float* W3    = (const float*)d_in[7];
  const float* b3    = (const float*)d_in[8];
  float* out = (float*)d_out;

  int N = in_sizes[0] / IN_CH;       // 8192
  int E = in_sizes[1] / 2;           // 262144
  int P = in_sizes[2] / 2;           // 65536
  int roww = (N + 31) >> 5;          // 256

  char* wsb = (char*)d_ws;
  uint32_t* bits = (uint32_t*)wsb;                       size_t off = (size_t)N * roww * 4;
  float* invlog  = (float*)(wsb + off);                  off += (size_t)N * 4;
  float* invdeg  = (float*)(wsb + off);                  off += (size_t)N * 4;
  int*   deg     = (int*)(wsb + off);                    off += (size_t)N * 4;
  float* nrm     = (float*)(wsb + off);                  off += (size_t)N * 4;
  ushort* adjl   = (ushort*)(wsb + off);                 off += (size_t)N * CAP * 2;
  ushort* w1pack = (ushort*)(wsb + off);                 off += (size_t)T1PACK * 8 * 2;
  ushort* w2pack = (ushort*)(wsb + off);                 off += (size_t)T2PACK * 8 * 2;

  int nwords = N * roww;
  k_prep<<<1024, 256, 0, stream>>>(W1, W2, w1pack, w2pack, bits, nwords);
  k_build_adj<<<(E + 255) / 256, 256, 0, stream>>>(ei, E, roww, bits);
  k_node_lists<<<(N + 3) / 4, 256, 0, stream>>>(bits, x, N, roww, invlog, invdeg, deg, nrm, adjl);
  k_mlp8<<<P / 64, 512, 0, stream>>>(x, pairs, bits, roww, deg, nrm, invlog, invdeg, adjl,
                                     w1pack, b1, w2pack, b2, W3, b3, out, P);
}

// Round 10
// 80.304 us; speedup vs baseline: 1.3470x; 1.0650x over previous
//
#include <hip/hip_runtime.h>
#include <hip/hip_bf16.h>

#define IN_CH   128
#define HIDDEN  256
#define H2DIM   128
#define KS1     17             // GEMM1 k-steps total (K=544); pass A: 0..7, pass B: 8..16
#define KS2     8              // GEMM2 k-steps (K=256)
#define NT1     16             // 256/16 n-tiles in GEMM1
#define NT2     8              // 128/16 n-tiles in GEMM2
#define FSTR    296            // feats LDS k-stride (ushort) for the half buffer
#define H1S     264            // h1 overlay stride (ushort)
#define CAP     64             // adjacency-list cap (fallback if deg>CAP)
#define T1PACK  (NT1*KS1*64)   // 17408
#define T2PACK  (NT2*KS2*64)   // 4096

typedef short short8v __attribute__((ext_vector_type(8)));
typedef float f32x4   __attribute__((ext_vector_type(4)));

__device__ __forceinline__ ushort f2bf(float f) {
  union { float f; uint32_t u; } c; c.f = f;
  uint32_t u = c.u + 0x7FFFu + ((c.u >> 16) & 1u);   // RNE
  return (ushort)(u >> 16);
}
__device__ __forceinline__ float bf2f(ushort h) {
  union { uint32_t u; float f; } c; c.u = ((uint32_t)h) << 16;
  return c.f;
}
__device__ __forceinline__ float bfLo(uint32_t u) { return bf2f((ushort)(u & 0xffffu)); }
__device__ __forceinline__ float bfHi(uint32_t u) { return bf2f((ushort)(u >> 16)); }
// packed RNE f32x2 -> bf16x2 via v_cvt_pk_bf16_f32
__device__ __forceinline__ uint32_t pk2(float a, float b) {
  __hip_bfloat162 h = __float22bfloat162_rn(make_float2(a, b));
  union { __hip_bfloat162 h; uint32_t u; } c; c.h = h;
  return c.u;
}
__device__ __forceinline__ uint4 pack8(float4 lo, float4 hi) {
  uint4 r;
  r.x = pk2(lo.x, lo.y); r.y = pk2(lo.z, lo.w);
  r.z = pk2(hi.x, hi.y); r.w = pk2(hi.z, hi.w);
  return r;
}

// ---------------- kernel 1: zero bitset + pack W1(K-folded)/W2 ----------------
// W1' k-order: [0,128): xu(A+E); [128,256): xv(B+E); [256,384): prod C;
// [384,512): absdiff D; [512,516): scalars; [516,544): zero pad
__global__ void k_prep(const float* __restrict__ W1, const float* __restrict__ W2,
                       ushort* __restrict__ w1p, ushort* __restrict__ w2p,
                       uint32_t* __restrict__ bits, int nwords) {
  int t = blockIdx.x * blockDim.x + threadIdx.x;
  if (t < T1PACK) {
    int l = t & 63;
    int rest = t >> 6;
    int ks = rest % KS1;
    int nt = rest / KS1;
    int n  = nt * 16 + (l & 15);
    int k0 = ks * 32 + (l >> 4) * 8;
    short8v v;
    #pragma unroll
    for (int j = 0; j < 8; ++j) {
      int k = k0 + j;
      float val;
      if (k < 128)      val = W1[(size_t)k * HIDDEN + n] + W1[(size_t)(512 + k) * HIDDEN + n];
      else if (k < 256) val = W1[(size_t)k * HIDDEN + n] + W1[(size_t)(384 + k) * HIDDEN + n];
      else if (k < 512) val = W1[(size_t)k * HIDDEN + n];
      else if (k < 516) val = W1[(size_t)(k + 128) * HIDDEN + n];   // rows 640..643
      else              val = 0.f;
      v[j] = (short)f2bf(val);
    }
    *(short8v*)(w1p + (size_t)t * 8) = v;
  } else if (t < T1PACK + T2PACK) {
    int t2 = t - T1PACK;
    int l = t2 & 63;
    int rest = t2 >> 6;
    int ks = rest % KS2;
    int nt = rest / KS2;
    int n  = nt * 16 + (l & 15);
    int k0 = ks * 32 + (l >> 4) * 8;
    short8v v;
    #pragma unroll
    for (int j = 0; j < 8; ++j)
      v[j] = (short)f2bf(W2[(size_t)(k0 + j) * H2DIM + n]);
    *(short8v*)(w2p + (size_t)t2 * 8) = v;
  }
  int stride = gridDim.x * blockDim.x;
  for (int i = t; i < nwords; i += stride) bits[i] = 0u;
}

// ---------------- kernel 2: build adjacency bitset ----------------
__global__ void k_build_adj(const int* __restrict__ ei, int E, int roww,
                            uint32_t* __restrict__ bits) {
  int e = blockIdx.x * blockDim.x + threadIdx.x;
  if (e >= E) return;
  int u = ei[e];
  int v = ei[E + e];
  if (u == v) return;
  atomicOr((unsigned int*)&bits[(size_t)u * roww + (v >> 5)], 1u << (v & 31));
}

// ---------------- kernel 3: degree stats + adjacency lists + node norms ----
__global__ void k_node_lists(const uint32_t* __restrict__ bits, const float* __restrict__ x,
                             int nnodes, int roww,
                             float* __restrict__ invlog, float* __restrict__ invdeg,
                             int* __restrict__ deg, float* __restrict__ nrm,
                             ushort* __restrict__ adjl) {
  int node = blockIdx.x * (blockDim.x >> 6) + (threadIdx.x >> 6);
  int lane = threadIdx.x & 63;
  if (node >= nnodes) return;
  const uint32_t* row = bits + (size_t)node * roww;
  uint32_t wd[4];
  int c = 0;
  #pragma unroll
  for (int j = 0; j < 4; ++j) { wd[j] = row[lane * 4 + j]; c += __popc(wd[j]); }
  int sum = c;
  #pragma unroll
  for (int off = 1; off < 64; off <<= 1) {
    int t = __shfl_up(sum, off);
    if (lane >= off) sum += t;
  }
  int excl = sum - c;
  int total = __shfl(sum, 63);
  ushort* lst = adjl + (size_t)node * CAP;
  int pos = excl;
  #pragma unroll
  for (int j = 0; j < 4; ++j) {
    uint32_t m = wd[j];
    int base = (lane * 4 + j) * 32;
    while (m) {
      int b = __ffs(m) - 1;
      if (pos < CAP) lst[pos] = (ushort)(base + b);
      ++pos;
      m &= m - 1;
    }
  }
  float2 xa = *(const float2*)(x + (size_t)node * IN_CH + 2 * lane);
  float ss = xa.x * xa.x + xa.y * xa.y;
  #pragma unroll
  for (int off = 32; off; off >>= 1) ss += __shfl_xor(ss, off);
  if (lane == 0) {
    deg[node] = total;
    float d = (float)total;
    invlog[node] = (total > 1) ? 1.0f / logf(d) : 0.0f;
    invdeg[node] = (total > 0) ? 1.0f / d : 0.0f;
    nrm[node] = sqrtf(ss);
  }
}

// ---------------- kernel 4: fused features + pair stats + MFMA MLP ----------
// 64 pairs/block, 512 threads (8 waves). Half-width feats buffer (64x296),
// GEMM1 split into two k-passes; pass B recomputes prod/absdiff from the
// bf16 xu/xv already in LDS. GEMM3 in-register. LDS ~38.9KB.
// launch_bounds(512,4): R5 evidence shows the compiler lands at exactly 64
// VGPR under this bound (no spill); 64 VGPR + 38.9KB LDS -> 4 blocks/CU.
__global__ __launch_bounds__(512, 4) void k_mlp9(
    const float* __restrict__ x, const int* __restrict__ pairs,
    const uint32_t* __restrict__ bits, int roww,
    const int* __restrict__ deg, const float* __restrict__ nrm,
    const float* __restrict__ invlog, const float* __restrict__ invdeg,
    const ushort* __restrict__ adjl,
    const ushort* __restrict__ w1p, const float* __restrict__ b1,
    const ushort* __restrict__ w2p, const float* __restrict__ b2,
    const float* __restrict__ W3, const float* __restrict__ b3,
    float* __restrict__ out, int P)
{
  __shared__ ushort feats[64 * FSTR];   // 37,888 B; h1 (stride 264) overlays later
  __shared__ float outacc[64];
  __shared__ int us[64], vs[64];

  int tid = threadIdx.x;
  int pb = blockIdx.x * 64;
  int w  = tid >> 6, l = tid & 63;
  int pg = l >> 3, g = l & 7;        // feature build: 8 lanes per pair
  int lr = l & 15;                   // MFMA A row / B,C col within tile
  int lk = l >> 4;                   // MFMA k-group / C row group

  if (tid < 64) {
    int2 pr = ((const int2*)pairs)[pb + tid];
    us[tid] = pr.x; vs[tid] = pr.y;
    outacc[tid] = b3[0];
  }
  __syncthreads();

  int p = w * 8 + pg;
  int u = us[p], v = vs[p];
  const float* xu = x + (size_t)u * IN_CH + g * 16;
  const float* xv = x + (size_t)v * IN_CH + g * 16;
  ushort* fpR = feats + p * FSTR;
  ushort* fp  = fpR + g * 16;

  // ---- pass A build: xu -> cols [0,128), xv -> cols [128,256), scalars 256..259,
  //      zero pad 260..287 ----
  {
    float4 a0 = *(const float4*)(xu + 0),  a1 = *(const float4*)(xu + 4);
    float4 a2 = *(const float4*)(xu + 8),  a3 = *(const float4*)(xu + 12);
    float4 b0 = *(const float4*)(xv + 0),  b1v = *(const float4*)(xv + 4);
    float4 b2v = *(const float4*)(xv + 8), b3v = *(const float4*)(xv + 12);
    *(uint4*)(fp)       = pack8(a0, a1);
    *(uint4*)(fp + 8)   = pack8(a2, a3);
    *(uint4*)(fp + 128) = pack8(b0, b1v);
    *(uint4*)(fp + 136) = pack8(b2v, b3v);
    float suv = a0.x*b0.x + a0.y*b0.y + a0.z*b0.z + a0.w*b0.w
              + a1.x*b1v.x + a1.y*b1v.y + a1.z*b1v.z + a1.w*b1v.w
              + a2.x*b2v.x + a2.y*b2v.y + a2.z*b2v.z + a2.w*b2v.w
              + a3.x*b3v.x + a3.y*b3v.y + a3.z*b3v.z + a3.w*b3v.w;
    suv += __shfl_xor(suv, 1);
    suv += __shfl_xor(suv, 2);
    suv += __shfl_xor(suv, 4);
    if (g == 0) fpR[256] = f2bf(suv / fmaxf(nrm[u] * nrm[v], 1e-8f));
    if (g < 7) *(uint2*)(fpR + 260 + 4 * g) = make_uint2(0u, 0u);
  }

  // ---- pair stats (ballot path; rare exact fallback) -> scalars 257..259 ----
  {
    int sdmin[8], snbs[8];
    uint32_t swrd[8];
    bool sfall = false;
    #pragma unroll
    for (int pp = 0; pp < 8; ++pp) {
      int ps_ = w * 8 + pp;
      int uu = us[ps_], vv = vs[ps_];
      int du = deg[uu], dv = deg[vv];
      int nu = adjl[(size_t)uu * CAP + l];
      int nv = adjl[(size_t)vv * CAP + l];
      bool ule = du <= dv;
      sdmin[pp] = ule ? du : dv;
      int o  = ule ? vv : uu;
      int nb = (ule ? nu : nv) & 8191;
      snbs[pp] = nb;
      swrd[pp] = bits[(size_t)o * roww + (nb >> 5)];
      sfall |= (sdmin[pp] > CAP);
    }
    if (!sfall) {
      #pragma unroll
      for (int pp = 0; pp < 8; ++pp) {
        bool h = (l < sdmin[pp]) && ((swrd[pp] >> (snbs[pp] & 31)) & 1u);
        unsigned long long mask = __ballot(h);
        float cnv = (float)__popcll(mask);
        float aa = 0.f, ra = 0.f;
        if (mask) {
          float il = 0.f, ig = 0.f;
          if (h) { il = invlog[snbs[pp]]; ig = invdeg[snbs[pp]]; }
          while (mask) {
            int ln = __ffsll(mask) - 1;
            aa += __shfl(il, ln);
            ra += __shfl(ig, ln);
            mask &= mask - 1;
          }
        }
        if (l == 0) {
          ushort* fq = feats + (w * 8 + pp) * FSTR;
          fq[257] = f2bf(cnv); fq[258] = f2bf(aa); fq[259] = f2bf(ra);
        }
      }
    } else {
      for (int pp = 0; pp < 8; ++pp) {
        int ps_ = w * 8 + pp;
        int uu = us[ps_], vv = vs[ps_];
        float cnL = 0.f, aaL = 0.f, raL = 0.f;
        const uint32_t* ru = bits + (size_t)uu * roww;
        const uint32_t* rv = bits + (size_t)vv * roww;
        for (int wd = l; wd < roww; wd += 64) {
          uint32_t c = ru[wd] & rv[wd];
          cnL += (float)__popc(c);
          while (c) {
            int bb = __ffs(c) - 1;
            int idx = wd * 32 + bb;
            aaL += invlog[idx]; raL += invdeg[idx];
            c &= c - 1;
          }
        }
        #pragma unroll
        for (int off = 32; off; off >>= 1) {
          cnL += __shfl_xor(cnL, off);
          aaL += __shfl_xor(aaL, off);
          raL += __shfl_xor(raL, off);
        }
        if (l == 0) {
          ushort* fq = feats + (w * 8 + pp) * FSTR;
          fq[257] = f2bf(cnL); fq[258] = f2bf(aaL); fq[259] = f2bf(raL);
        }
      }
    }
  }
  __syncthreads();

  // ---- GEMM1 accumulators persist across both k-passes ----
  f32x4 acc[4][2];
  #pragma unroll
  for (int m = 0; m < 4; ++m)
    #pragma unroll
    for (int i = 0; i < 2; ++i) acc[m][i] = (f32x4){0.f, 0.f, 0.f, 0.f};

  const ushort* aB = feats + lr * FSTR + lk * 8;
  const ushort* bW = w1p + (size_t)(w * 2) * KS1 * 512 + l * 8;

  // ---- GEMM1 pass A: ks 0..7 (k 0..255) ----
  {
    short8v bf[2][2];
    #pragma unroll
    for (int i = 0; i < 2; ++i)
      bf[0][i] = *(const short8v*)(bW + (size_t)(i * KS1) * 512);
    #pragma unroll
    for (int ks = 0; ks < 8; ++ks) {
      int cur = ks & 1, nxt = cur ^ 1;
      if (ks + 1 < 8) {
        #pragma unroll
        for (int i = 0; i < 2; ++i)
          bf[nxt][i] = *(const short8v*)(bW + (size_t)(i * KS1 + ks + 1) * 512);
      }
      short8v am[4];
      #pragma unroll
      for (int m = 0; m < 4; ++m)
        am[m] = *(const short8v*)(aB + m * 16 * FSTR + ks * 32);
      #pragma unroll
      for (int i = 0; i < 2; ++i)
        #pragma unroll
        for (int m = 0; m < 4; ++m)
          acc[m][i] = __builtin_amdgcn_mfma_f32_16x16x32_bf16(am[m], bf[cur][i], acc[m][i], 0, 0, 0);
    }
  }
  __syncthreads();   // all waves done reading pass-A cols

  // ---- pass B build: read bf16 xu/xv back from LDS; prod -> [0,128),
  //      absdiff -> [128,256). Same-thread same-cells: no cross-thread hazard.
  {
    uint4 A0 = *(uint4*)(fp);
    uint4 A1 = *(uint4*)(fp + 8);
    uint4 B0 = *(uint4*)(fp + 128);
    uint4 B1 = *(uint4*)(fp + 136);
    uint4 P0, P1, D0, D1;
    #define PD(Au, Bu, Pu, Du)                                                 \
      {                                                                        \
        float alo = bfLo(Au), ahi = bfHi(Au);                                  \
        float blo = bfLo(Bu), bhi = bfHi(Bu);                                  \
        Pu = pk2(alo * blo, ahi * bhi);                                        \
        Du = pk2(fabsf(alo - blo), fabsf(ahi - bhi));                          \
      }
    PD(A0.x, B0.x, P0.x, D0.x) PD(A0.y, B0.y, P0.y, D0.y)
    PD(A0.z, B0.z, P0.z, D0.z) PD(A0.w, B0.w, P0.w, D0.w)
    PD(A1.x, B1.x, P1.x, D1.x) PD(A1.y, B1.y, P1.y, D1.y)
    PD(A1.z, B1.z, P1.z, D1.z) PD(A1.w, B1.w, P1.w, D1.w)
    #undef PD
    *(uint4*)(fp)       = P0;
    *(uint4*)(fp + 8)   = P1;
    *(uint4*)(fp + 128) = D0;
    *(uint4*)(fp + 136) = D1;
  }
  __syncthreads();

  // ---- GEMM1 pass B: ks 8..16 (k 256..543; buffer col = (ks-8)*32) ----
  {
    short8v bf[2][2];
    #pragma unroll
    for (int i = 0; i < 2; ++i)
      bf[0][i] = *(const short8v*)(bW + (size_t)(i * KS1 + 8) * 512);
    #pragma unroll
    for (int ks = 8; ks < KS1; ++ks) {
      int cur = ks & 1, nxt = cur ^ 1;
      if (ks + 1 < KS1) {
        #pragma unroll
        for (int i = 0; i < 2; ++i)
          bf[nxt][i] = *(const short8v*)(bW + (size_t)(i * KS1 + ks + 1) * 512);
      }
      short8v am[4];
      #pragma unroll
      for (int m = 0; m < 4; ++m)
        am[m] = *(const short8v*)(aB + m * 16 * FSTR + (ks - 8) * 32);
      #pragma unroll
      for (int i = 0; i < 2; ++i)
        #pragma unroll
        for (int m = 0; m < 4; ++m)
          acc[m][i] = __builtin_amdgcn_mfma_f32_16x16x32_bf16(am[m], bf[cur][i], acc[m][i], 0, 0, 0);
    }
  }

  // bias1 + ReLU + bf16 into regs; overlay h1 into feats after barrier
  uint32_t h1r[2][8];
  #pragma unroll
  for (int i = 0; i < 2; ++i) {
    float bias = b1[(w * 2 + i) * 16 + lr];
    #pragma unroll
    for (int m = 0; m < 4; ++m) {
      float v0 = fmaxf(acc[m][i][0] + bias, 0.f);
      float v1 = fmaxf(acc[m][i][1] + bias, 0.f);
      float v2 = fmaxf(acc[m][i][2] + bias, 0.f);
      float v3 = fmaxf(acc[m][i][3] + bias, 0.f);
      h1r[i][m * 2]     = pk2(v0, v1);
      h1r[i][m * 2 + 1] = pk2(v2, v3);
    }
  }
  __syncthreads();   // pass-B buffer fully consumed

  ushort* h1 = feats;   // flat overlay [row*H1S + col]
  #pragma unroll
  for (int i = 0; i < 2; ++i) {
    int col = (w * 2 + i) * 16 + lr;
    #pragma unroll
    for (int m = 0; m < 4; ++m) {
      int row0 = m * 16 + lk * 4;
      h1[(row0)     * H1S + col] = (ushort)(h1r[i][m * 2]);
      h1[(row0 + 1) * H1S + col] = (ushort)(h1r[i][m * 2] >> 16);
      h1[(row0 + 2) * H1S + col] = (ushort)(h1r[i][m * 2 + 1]);
      h1[(row0 + 3) * H1S + col] = (ushort)(h1r[i][m * 2 + 1] >> 16);
    }
  }
  __syncthreads();

  // ---- GEMM2: h1[64x256] @ W2[256x128]; wave w owns n-tile w ----
  f32x4 acc2[4];
  #pragma unroll
  for (int m = 0; m < 4; ++m) acc2[m] = (f32x4){0.f, 0.f, 0.f, 0.f};

  const ushort* aB2 = h1 + lr * H1S + lk * 8;
  const ushort* bW2 = w2p + (size_t)w * KS2 * 512 + l * 8;

  short8v b2f[2];
  b2f[0] = *(const short8v*)(bW2);

  #pragma unroll
  for (int ks = 0; ks < KS2; ++ks) {
    int cur = ks & 1, nxt = cur ^ 1;
    if (ks + 1 < KS2)
      b2f[nxt] = *(const short8v*)(bW2 + (size_t)(ks + 1) * 512);
    #pragma unroll
    for (int m = 0; m < 4; ++m) {
      short8v am = *(const short8v*)(aB2 + m * 16 * H1S + ks * 32);
      acc2[m] = __builtin_amdgcn_mfma_f32_16x16x32_bf16(am, b2f[cur], acc2[m], 0, 0, 0);
    }
  }

  // ---- GEMM3 in-register: lane col = w*16+lr; shfl-reduce then LDS atomicAdd ----
  {
    int col = w * 16 + lr;
    float bias = b2[col];
    float w3v = W3[col];
    #pragma unroll
    for (int m = 0; m < 4; ++m) {
      #pragma unroll
      for (int r = 0; r < 4; ++r) {
        float h = fmaxf(acc2[m][r] + bias, 0.f) * w3v;
        h += __shfl_xor(h, 1);
        h += __shfl_xor(h, 2);
        h += __shfl_xor(h, 4);
        h += __shfl_xor(h, 8);
        if (lr == 0) atomicAdd(&outacc[m * 16 + lk * 4 + r], h);
      }
    }
  }
  __syncthreads();

  if (tid < 64) out[pb + tid] = outacc[tid];
}

extern "C" void kernel_launch(void* const* d_in, const int* in_sizes, int n_in,
                              void* d_out, int out_size, void* d_ws, size_t ws_size,
                              hipStream_t stream) {
  const float* x     = (const float*)d_in[0];
  const int*   ei    = (const int*)d_in[1];
  const int*   pairs = (const int*)d_in[2];
  const float* W1    = (const float*)d_in[3];
  const float* b1    = (const float*)d_in[4];
  const float* W2    = (const float*)d_in[5];
  const float* b2    = (const float*)d_in[6];
  const float* W3    = (const float*)d_in[7];
  const float* b3    = (const float*)d_in[8];
  float* out = (float*)d_out;

  int N = in_sizes[0] / IN_CH;       // 8192
  int E = in_sizes[1] / 2;           // 262144
  int P = in_sizes[2] / 2;           // 65536
  int roww = (N + 31) >> 5;          // 256

  char* wsb = (char*)d_ws;
  uint32_t* bits = (uint32_t*)wsb;                       size_t off = (size_t)N * roww * 4;
  float* invlog  = (float*)(wsb + off);                  off += (size_t)N * 4;
  float* invdeg  = (float*)(wsb + off);                  off += (size_t)N * 4;
  int*   deg     = (int*)(wsb + off);                    off += (size_t)N * 4;
  float* nrm     = (float*)(wsb + off);                  off += (size_t)N * 4;
  ushort* adjl   = (ushort*)(wsb + off);                 off += (size_t)N * CAP * 2;
  ushort* w1pack = (ushort*)(wsb + off);                 off += (size_t)T1PACK * 8 * 2;
  ushort* w2pack = (ushort*)(wsb + off);                 off += (size_t)T2PACK * 8 * 2;

  int nwords = N * roww;
  k_prep<<<1024, 256, 0, stream>>>(W1, W2, w1pack, w2pack, bits, nwords);
  k_build_adj<<<(E + 255) / 256, 256, 0, stream>>>(ei, E, roww, bits);
  k_node_lists<<<(N + 3) / 4, 256, 0, stream>>>(bits, x, N, roww, invlog, invdeg, deg, nrm, adjl);
  k_mlp9<<<P / 64, 512, 0, stream>>>(x, pairs, bits, roww, deg, nrm, invlog, invdeg, adjl,
                                     w1pack, b1, w2pack, b2, W3, b3, out, P);
}

// Round 11
// 79.231 us; speedup vs baseline: 1.3652x; 1.0135x over previous
//
#include <hip/hip_runtime.h>
#include <hip/hip_bf16.h>

#define IN_CH   128
#define HIDDEN  256
#define H2DIM   128
#define KS1     17             // GEMM1 k-steps total (K=544); pass A: 0..7, pass B: 8..16
#define KS2     8              // GEMM2 k-steps (K=256)
#define NT1     16             // 256/16 n-tiles in GEMM1
#define NT2     8              // 128/16 n-tiles in GEMM2
#define FSTR    296            // feats LDS k-stride (ushort) for the half buffer
#define H1S     264            // h1 overlay stride (ushort)
#define CAP     64             // adjacency-list cap (fallback if deg>CAP)
#define T1PACK  (NT1*KS1*64)   // 17408
#define T2PACK  (NT2*KS2*64)   // 4096

typedef short short8v __attribute__((ext_vector_type(8)));
typedef float f32x4   __attribute__((ext_vector_type(4)));

__device__ __forceinline__ ushort f2bf(float f) {
  union { float f; uint32_t u; } c; c.f = f;
  uint32_t u = c.u + 0x7FFFu + ((c.u >> 16) & 1u);   // RNE
  return (ushort)(u >> 16);
}
__device__ __forceinline__ float bf2f(ushort h) {
  union { uint32_t u; float f; } c; c.u = ((uint32_t)h) << 16;
  return c.f;
}
__device__ __forceinline__ float bfLo(uint32_t u) { return bf2f((ushort)(u & 0xffffu)); }
__device__ __forceinline__ float bfHi(uint32_t u) { return bf2f((ushort)(u >> 16)); }
// packed RNE f32x2 -> bf16x2 via v_cvt_pk_bf16_f32
__device__ __forceinline__ uint32_t pk2(float a, float b) {
  __hip_bfloat162 h = __float22bfloat162_rn(make_float2(a, b));
  union { __hip_bfloat162 h; uint32_t u; } c; c.h = h;
  return c.u;
}

// ---------------- kernel 1: zero bitset + pack W1(K-folded)/W2 ----------------
// W1' k-order: [0,128): xu(A+E); [128,256): xv(B+E); [256,384): prod C;
// [384,512): absdiff D; [512,516): scalars; [516,544): zero pad
__global__ void k_prep(const float* __restrict__ W1, const float* __restrict__ W2,
                       ushort* __restrict__ w1p, ushort* __restrict__ w2p,
                       uint32_t* __restrict__ bits, int nwords) {
  int t = blockIdx.x * blockDim.x + threadIdx.x;
  if (t < T1PACK) {
    int l = t & 63;
    int rest = t >> 6;
    int ks = rest % KS1;
    int nt = rest / KS1;
    int n  = nt * 16 + (l & 15);
    int k0 = ks * 32 + (l >> 4) * 8;
    short8v v;
    #pragma unroll
    for (int j = 0; j < 8; ++j) {
      int k = k0 + j;
      float val;
      if (k < 128)      val = W1[(size_t)k * HIDDEN + n] + W1[(size_t)(512 + k) * HIDDEN + n];
      else if (k < 256) val = W1[(size_t)k * HIDDEN + n] + W1[(size_t)(384 + k) * HIDDEN + n];
      else if (k < 512) val = W1[(size_t)k * HIDDEN + n];
      else if (k < 516) val = W1[(size_t)(k + 128) * HIDDEN + n];   // rows 640..643
      else              val = 0.f;
      v[j] = (short)f2bf(val);
    }
    *(short8v*)(w1p + (size_t)t * 8) = v;
  } else if (t < T1PACK + T2PACK) {
    int t2 = t - T1PACK;
    int l = t2 & 63;
    int rest = t2 >> 6;
    int ks = rest % KS2;
    int nt = rest / KS2;
    int n  = nt * 16 + (l & 15);
    int k0 = ks * 32 + (l >> 4) * 8;
    short8v v;
    #pragma unroll
    for (int j = 0; j < 8; ++j)
      v[j] = (short)f2bf(W2[(size_t)(k0 + j) * H2DIM + n]);
    *(short8v*)(w2p + (size_t)t2 * 8) = v;
  }
  int stride = gridDim.x * blockDim.x;
  for (int i = t; i < nwords; i += stride) bits[i] = 0u;
}

// ---------------- kernel 2: build adjacency bitset ----------------
__global__ void k_build_adj(const int* __restrict__ ei, int E, int roww,
                            uint32_t* __restrict__ bits) {
  int e = blockIdx.x * blockDim.x + threadIdx.x;
  if (e >= E) return;
  int u = ei[e];
  int v = ei[E + e];
  if (u == v) return;
  atomicOr((unsigned int*)&bits[(size_t)u * roww + (v >> 5)], 1u << (v & 31));
}

// ------- kernel 3: degree stats + adjacency lists + node norms + bf16 x copy --
__global__ void k_node_lists(const uint32_t* __restrict__ bits, const float* __restrict__ x,
                             int nnodes, int roww,
                             float* __restrict__ invlog, float* __restrict__ invdeg,
                             int* __restrict__ deg, float* __restrict__ nrm,
                             ushort* __restrict__ adjl, ushort* __restrict__ xbf) {
  int node = blockIdx.x * (blockDim.x >> 6) + (threadIdx.x >> 6);
  int lane = threadIdx.x & 63;
  if (node >= nnodes) return;
  const uint32_t* row = bits + (size_t)node * roww;
  uint32_t wd[4];
  int c = 0;
  #pragma unroll
  for (int j = 0; j < 4; ++j) { wd[j] = row[lane * 4 + j]; c += __popc(wd[j]); }
  int sum = c;
  #pragma unroll
  for (int off = 1; off < 64; off <<= 1) {
    int t = __shfl_up(sum, off);
    if (lane >= off) sum += t;
  }
  int excl = sum - c;
  int total = __shfl(sum, 63);
  ushort* lst = adjl + (size_t)node * CAP;
  int pos = excl;
  #pragma unroll
  for (int j = 0; j < 4; ++j) {
    uint32_t m = wd[j];
    int base = (lane * 4 + j) * 32;
    while (m) {
      int b = __ffs(m) - 1;
      if (pos < CAP) lst[pos] = (ushort)(base + b);
      ++pos;
      m &= m - 1;
    }
  }
  float2 xa = *(const float2*)(x + (size_t)node * IN_CH + 2 * lane);
  // bf16 copy of x (coalesced 4B/lane)
  *(uint32_t*)(xbf + (size_t)node * IN_CH + 2 * lane) = pk2(xa.x, xa.y);
  float ss = xa.x * xa.x + xa.y * xa.y;
  #pragma unroll
  for (int off = 32; off; off >>= 1) ss += __shfl_xor(ss, off);
  if (lane == 0) {
    deg[node] = total;
    float d = (float)total;
    invlog[node] = (total > 1) ? 1.0f / logf(d) : 0.0f;
    invdeg[node] = (total > 0) ? 1.0f / d : 0.0f;
    nrm[node] = sqrtf(ss);
  }
}

// ---------------- kernel 4: fused features + pair stats + MFMA MLP ----------
// 64 pairs/block, 512 threads (8 waves). Gathers x as bf16 (xbf, 2MB) to halve
// L2-miss traffic. Half-width feats buffer, 2-pass GEMM1, in-register GEMM3.
__global__ __launch_bounds__(512, 4) void k_mlp10(
    const ushort* __restrict__ xbf, const int* __restrict__ pairs,
    const uint32_t* __restrict__ bits, int roww,
    const int* __restrict__ deg, const float* __restrict__ nrm,
    const float* __restrict__ invlog, const float* __restrict__ invdeg,
    const ushort* __restrict__ adjl,
    const ushort* __restrict__ w1p, const float* __restrict__ b1,
    const ushort* __restrict__ w2p, const float* __restrict__ b2,
    const float* __restrict__ W3, const float* __restrict__ b3,
    float* __restrict__ out, int P)
{
  __shared__ ushort feats[64 * FSTR];   // 37,888 B; h1 (stride 264) overlays later
  __shared__ float outacc[64];
  __shared__ int us[64], vs[64];

  int tid = threadIdx.x;
  int pb = blockIdx.x * 64;
  int w  = tid >> 6, l = tid & 63;
  int pg = l >> 3, g = l & 7;        // feature build: 8 lanes per pair
  int lr = l & 15;                   // MFMA A row / B,C col within tile
  int lk = l >> 4;                   // MFMA k-group / C row group

  if (tid < 64) {
    int2 pr = ((const int2*)pairs)[pb + tid];
    us[tid] = pr.x; vs[tid] = pr.y;
    outacc[tid] = b3[0];
  }
  __syncthreads();

  int p = w * 8 + pg;
  int u = us[p], v = vs[p];
  ushort* fpR = feats + p * FSTR;
  ushort* fp  = fpR + g * 16;

  // ---- pass A build: bf16 xu -> cols [0,128), xv -> [128,256); cos; pad ----
  {
    const ushort* xup = xbf + (size_t)u * IN_CH + g * 16;
    const ushort* xvp = xbf + (size_t)v * IN_CH + g * 16;
    uint4 A0 = *(const uint4*)(xup);
    uint4 A1 = *(const uint4*)(xup + 8);
    uint4 B0 = *(const uint4*)(xvp);
    uint4 B1 = *(const uint4*)(xvp + 8);
    *(uint4*)(fp)       = A0;
    *(uint4*)(fp + 8)   = A1;
    *(uint4*)(fp + 128) = B0;
    *(uint4*)(fp + 136) = B1;
    float suv = bfLo(A0.x)*bfLo(B0.x) + bfHi(A0.x)*bfHi(B0.x)
              + bfLo(A0.y)*bfLo(B0.y) + bfHi(A0.y)*bfHi(B0.y)
              + bfLo(A0.z)*bfLo(B0.z) + bfHi(A0.z)*bfHi(B0.z)
              + bfLo(A0.w)*bfLo(B0.w) + bfHi(A0.w)*bfHi(B0.w)
              + bfLo(A1.x)*bfLo(B1.x) + bfHi(A1.x)*bfHi(B1.x)
              + bfLo(A1.y)*bfLo(B1.y) + bfHi(A1.y)*bfHi(B1.y)
              + bfLo(A1.z)*bfLo(B1.z) + bfHi(A1.z)*bfHi(B1.z)
              + bfLo(A1.w)*bfLo(B1.w) + bfHi(A1.w)*bfHi(B1.w);
    suv += __shfl_xor(suv, 1);
    suv += __shfl_xor(suv, 2);
    suv += __shfl_xor(suv, 4);
    if (g == 0) fpR[256] = f2bf(suv / fmaxf(nrm[u] * nrm[v], 1e-8f));
    if (g < 7) *(uint2*)(fpR + 260 + 4 * g) = make_uint2(0u, 0u);
  }

  // ---- pair stats (ballot path; rare exact fallback) -> scalars 257..259 ----
  {
    int sdmin[8], snbs[8];
    uint32_t swrd[8];
    bool sfall = false;
    #pragma unroll
    for (int pp = 0; pp < 8; ++pp) {
      int ps_ = w * 8 + pp;
      int uu = us[ps_], vv = vs[ps_];
      int du = deg[uu], dv = deg[vv];
      int nu = adjl[(size_t)uu * CAP + l];
      int nv = adjl[(size_t)vv * CAP + l];
      bool ule = du <= dv;
      sdmin[pp] = ule ? du : dv;
      int o  = ule ? vv : uu;
      int nb = (ule ? nu : nv) & 8191;
      snbs[pp] = nb;
      swrd[pp] = bits[(size_t)o * roww + (nb >> 5)];
      sfall |= (sdmin[pp] > CAP);
    }
    if (!sfall) {
      #pragma unroll
      for (int pp = 0; pp < 8; ++pp) {
        bool h = (l < sdmin[pp]) && ((swrd[pp] >> (snbs[pp] & 31)) & 1u);
        unsigned long long mask = __ballot(h);
        float cnv = (float)__popcll(mask);
        float aa = 0.f, ra = 0.f;
        if (mask) {
          float il = 0.f, ig = 0.f;
          if (h) { il = invlog[snbs[pp]]; ig = invdeg[snbs[pp]]; }
          while (mask) {
            int ln = __ffsll(mask) - 1;
            aa += __shfl(il, ln);
            ra += __shfl(ig, ln);
            mask &= mask - 1;
          }
        }
        if (l == 0) {
          ushort* fq = feats + (w * 8 + pp) * FSTR;
          fq[257] = f2bf(cnv); fq[258] = f2bf(aa); fq[259] = f2bf(ra);
        }
      }
    } else {
      for (int pp = 0; pp < 8; ++pp) {
        int ps_ = w * 8 + pp;
        int uu = us[ps_], vv = vs[ps_];
        float cnL = 0.f, aaL = 0.f, raL = 0.f;
        const uint32_t* ru = bits + (size_t)uu * roww;
        const uint32_t* rv = bits + (size_t)vv * roww;
        for (int wd = l; wd < roww; wd += 64) {
          uint32_t c = ru[wd] & rv[wd];
          cnL += (float)__popc(c);
          while (c) {
            int bb = __ffs(c) - 1;
            int idx = wd * 32 + bb;
            aaL += invlog[idx]; raL += invdeg[idx];
            c &= c - 1;
          }
        }
        #pragma unroll
        for (int off = 32; off; off >>= 1) {
          cnL += __shfl_xor(cnL, off);
          aaL += __shfl_xor(aaL, off);
          raL += __shfl_xor(raL, off);
        }
        if (l == 0) {
          ushort* fq = feats + (w * 8 + pp) * FSTR;
          fq[257] = f2bf(cnL); fq[258] = f2bf(aaL); fq[259] = f2bf(raL);
        }
      }
    }
  }
  __syncthreads();

  // ---- GEMM1 accumulators persist across both k-passes ----
  f32x4 acc[4][2];
  #pragma unroll
  for (int m = 0; m < 4; ++m)
    #pragma unroll
    for (int i = 0; i < 2; ++i) acc[m][i] = (f32x4){0.f, 0.f, 0.f, 0.f};

  const ushort* aB = feats + lr * FSTR + lk * 8;
  const ushort* bW = w1p + (size_t)(w * 2) * KS1 * 512 + l * 8;

  // ---- GEMM1 pass A: ks 0..7 (k 0..255) ----
  {
    short8v bf[2][2];
    #pragma unroll
    for (int i = 0; i < 2; ++i)
      bf[0][i] = *(const short8v*)(bW + (size_t)(i * KS1) * 512);
    #pragma unroll
    for (int ks = 0; ks < 8; ++ks) {
      int cur = ks & 1, nxt = cur ^ 1;
      if (ks + 1 < 8) {
        #pragma unroll
        for (int i = 0; i < 2; ++i)
          bf[nxt][i] = *(const short8v*)(bW + (size_t)(i * KS1 + ks + 1) * 512);
      }
      short8v am[4];
      #pragma unroll
      for (int m = 0; m < 4; ++m)
        am[m] = *(const short8v*)(aB + m * 16 * FSTR + ks * 32);
      #pragma unroll
      for (int i = 0; i < 2; ++i)
        #pragma unroll
        for (int m = 0; m < 4; ++m)
          acc[m][i] = __builtin_amdgcn_mfma_f32_16x16x32_bf16(am[m], bf[cur][i], acc[m][i], 0, 0, 0);
    }
  }
  __syncthreads();   // all waves done reading pass-A cols

  // ---- pass B build: read bf16 xu/xv back from LDS; prod -> [0,128),
  //      absdiff -> [128,256). Same-thread same-cells: no cross-thread hazard.
  {
    uint4 A0 = *(uint4*)(fp);
    uint4 A1 = *(uint4*)(fp + 8);
    uint4 B0 = *(uint4*)(fp + 128);
    uint4 B1 = *(uint4*)(fp + 136);
    uint4 P0, P1, D0, D1;
    #define PD(Au, Bu, Pu, Du)                                                 \
      {                                                                        \
        float alo = bfLo(Au), ahi = bfHi(Au);                                  \
        float blo = bfLo(Bu), bhi = bfHi(Bu);                                  \
        Pu = pk2(alo * blo, ahi * bhi);                                        \
        Du = pk2(fabsf(alo - blo), fabsf(ahi - bhi));                          \
      }
    PD(A0.x, B0.x, P0.x, D0.x) PD(A0.y, B0.y, P0.y, D0.y)
    PD(A0.z, B0.z, P0.z, D0.z) PD(A0.w, B0.w, P0.w, D0.w)
    PD(A1.x, B1.x, P1.x, D1.x) PD(A1.y, B1.y, P1.y, D1.y)
    PD(A1.z, B1.z, P1.z, D1.z) PD(A1.w, B1.w, P1.w, D1.w)
    #undef PD
    *(uint4*)(fp)       = P0;
    *(uint4*)(fp + 8)   = P1;
    *(uint4*)(fp + 128) = D0;
    *(uint4*)(fp + 136) = D1;
  }
  __syncthreads();

  // ---- GEMM1 pass B: ks 8..16 (k 256..543; buffer col = (ks-8)*32) ----
  {
    short8v bf[2][2];
    #pragma unroll
    for (int i = 0; i < 2; ++i)
      bf[0][i] = *(const short8v*)(bW + (size_t)(i * KS1 + 8) * 512);
    #pragma unroll
    for (int ks = 8; ks < KS1; ++ks) {
      int cur = ks & 1, nxt = cur ^ 1;
      if (ks + 1 < KS1) {
        #pragma unroll
        for (int i = 0; i < 2; ++i)
          bf[nxt][i] = *(const short8v*)(bW + (size_t)(i * KS1 + ks + 1) * 512);
      }
      short8v am[4];
      #pragma unroll
      for (int m = 0; m < 4; ++m)
        am[m] = *(const short8v*)(aB + m * 16 * FSTR + (ks - 8) * 32);
      #pragma unroll
      for (int i = 0; i < 2; ++i)
        #pragma unroll
        for (int m = 0; m < 4; ++m)
          acc[m][i] = __builtin_amdgcn_mfma_f32_16x16x32_bf16(am[m], bf[cur][i], acc[m][i], 0, 0, 0);
    }
  }

  // bias1 + ReLU + bf16 into regs; overlay h1 into feats after barrier
  uint32_t h1r[2][8];
  #pragma unroll
  for (int i = 0; i < 2; ++i) {
    float bias = b1[(w * 2 + i) * 16 + lr];
    #pragma unroll
    for (int m = 0; m < 4; ++m) {
      float v0 = fmaxf(acc[m][i][0] + bias, 0.f);
      float v1 = fmaxf(acc[m][i][1] + bias, 0.f);
      float v2 = fmaxf(acc[m][i][2] + bias, 0.f);
      float v3 = fmaxf(acc[m][i][3] + bias, 0.f);
      h1r[i][m * 2]     = pk2(v0, v1);
      h1r[i][m * 2 + 1] = pk2(v2, v3);
    }
  }
  __syncthreads();   // pass-B buffer fully consumed

  ushort* h1 = feats;   // flat overlay [row*H1S + col]
  #pragma unroll
  for (int i = 0; i < 2; ++i) {
    int col = (w * 2 + i) * 16 + lr;
    #pragma unroll
    for (int m = 0; m < 4; ++m) {
      int row0 = m * 16 + lk * 4;
      h1[(row0)     * H1S + col] = (ushort)(h1r[i][m * 2]);
      h1[(row0 + 1) * H1S + col] = (ushort)(h1r[i][m * 2] >> 16);
      h1[(row0 + 2) * H1S + col] = (ushort)(h1r[i][m * 2 + 1]);
      h1[(row0 + 3) * H1S + col] = (ushort)(h1r[i][m * 2 + 1] >> 16);
    }
  }
  __syncthreads();

  // ---- GEMM2: h1[64x256] @ W2[256x128]; wave w owns n-tile w ----
  f32x4 acc2[4];
  #pragma unroll
  for (int m = 0; m < 4; ++m) acc2[m] = (f32x4){0.f, 0.f, 0.f, 0.f};

  const ushort* aB2 = h1 + lr * H1S + lk * 8;
  const ushort* bW2 = w2p + (size_t)w * KS2 * 512 + l * 8;

  short8v b2f[2];
  b2f[0] = *(const short8v*)(bW2);

  #pragma unroll
  for (int ks = 0; ks < KS2; ++ks) {
    int cur = ks & 1, nxt = cur ^ 1;
    if (ks + 1 < KS2)
      b2f[nxt] = *(const short8v*)(bW2 + (size_t)(ks + 1) * 512);
    #pragma unroll
    for (int m = 0; m < 4; ++m) {
      short8v am = *(const short8v*)(aB2 + m * 16 * H1S + ks * 32);
      acc2[m] = __builtin_amdgcn_mfma_f32_16x16x32_bf16(am, b2f[cur], acc2[m], 0, 0, 0);
    }
  }

  // ---- GEMM3 in-register: lane col = w*16+lr; shfl-reduce then LDS atomicAdd ----
  {
    int col = w * 16 + lr;
    float bias = b2[col];
    float w3v = W3[col];
    #pragma unroll
    for (int m = 0; m < 4; ++m) {
      #pragma unroll
      for (int r = 0; r < 4; ++r) {
        float h = fmaxf(acc2[m][r] + bias, 0.f) * w3v;
        h += __shfl_xor(h, 1);
        h += __shfl_xor(h, 2);
        h += __shfl_xor(h, 4);
        h += __shfl_xor(h, 8);
        if (lr == 0) atomicAdd(&outacc[m * 16 + lk * 4 + r], h);
      }
    }
  }
  __syncthreads();

  if (tid < 64) out[pb + tid] = outacc[tid];
}

extern "C" void kernel_launch(void* const* d_in, const int* in_sizes, int n_in,
                              void* d_out, int out_size, void* d_ws, size_t ws_size,
                              hipStream_t stream) {
  const float* x     = (const float*)d_in[0];
  const int*   ei    = (const int*)d_in[1];
  const int*   pairs = (const int*)d_in[2];
  const float* W1    = (const float*)d_in[3];
  const float* b1    = (const float*)d_in[4];
  const float* W2    = (const float*)d_in[5];
  const float* b2    = (const float*)d_in[6];
  const float* W3    = (const float*)d_in[7];
  const float* b3    = (const float*)d_in[8];
  float* out = (float*)d_out;

  int N = in_sizes[0] / IN_CH;       // 8192
  int E = in_sizes[1] / 2;           // 262144
  int P = in_sizes[2] / 2;           // 65536
  int roww = (N + 31) >> 5;          // 256

  char* wsb = (char*)d_ws;
  uint32_t* bits = (uint32_t*)wsb;                       size_t off = (size_t)N * roww * 4;
  float* invlog  = (float*)(wsb + off);                  off += (size_t)N * 4;
  float* invdeg  = (float*)(wsb + off);                  off += (size_t)N * 4;
  int*   deg     = (int*)(wsb + off);                    off += (size_t)N * 4;
  float* nrm     = (float*)(wsb + off);                  off += (size_t)N * 4;
  ushort* adjl   = (ushort*)(wsb + off);                 off += (size_t)N * CAP * 2;
  ushort* xbf    = (ushort*)(wsb + off);                 off += (size_t)N * IN_CH * 2;
  ushort* w1pack = (ushort*)(wsb + off);                 off += (size_t)T1PACK * 8 * 2;
  ushort* w2pack = (ushort*)(wsb + off);                 off += (size_t)T2PACK * 8 * 2;

  int nwords = N * roww;
  k_prep<<<1024, 256, 0, stream>>>(W1, W2, w1pack, w2pack, bits, nwords);
  k_build_adj<<<(E + 255) / 256, 256, 0, stream>>>(ei, E, roww, bits);
  k_node_lists<<<(N + 3) / 4, 256, 0, stream>>>(bits, x, N, roww, invlog, invdeg, deg, nrm, adjl, xbf);
  k_mlp10<<<P / 64, 512, 0, stream>>>(xbf, pairs, bits, roww, deg, nrm, invlog, invdeg, adjl,
                                      w1pack, b1, w2pack, b2, W3, b3, out, P);
}